// Round 1
// baseline (309.363 us; speedup 1.0000x reference)
//
#include <hip/hip_runtime.h>

// Shapes fixed by reference setup_inputs(): B=8, H=16, W=16, L=64, C=64.
// out[b, p, l, n, c] = E[b, h+dy[n], w+dx[n], l, c]  (0 if neighbor off-grid)
// All dims are powers of two -> pure shift/mask index math.

constexpr unsigned Bb = 8, Hh = 16, Ww = 16, Ll = 64, Cc = 64;
constexpr unsigned C4   = Cc / 4;                               // 16 float4 per (b,p,l,n) row
constexpr unsigned OUT4 = Bb * Hh * Ww * Ll * 8u * C4;          // 2^24 float4 stores

// Packed (d+1) 2-bit LUTs for the 8 neighbor offsets, n=0 at LSB:
//   offsets: (-1,-1)(-1,0)(-1,1)(0,-1)(0,1)(1,-1)(1,0)(1,1)
//   dy+1 = 0,0,0,1,1,2,2,2 -> 0xA940
//   dx+1 = 0,1,2,0,2,0,1,2 -> 0x9224
__global__ __launch_bounds__(256) void patch_neighbor_gather(
    const float4* __restrict__ in, float4* __restrict__ out) {
  unsigned i = blockIdx.x * blockDim.x + threadIdx.x;
  const unsigned stride = gridDim.x * blockDim.x;
  const float4 zero = make_float4(0.f, 0.f, 0.f, 0.f);
  for (; i < OUT4; i += stride) {
    // out flat (float4 units): ((((b*256 + p)*64 + l)*8 + n)*16 + c4)
    const unsigned c4 = i & 15u;
    const unsigned n  = (i >> 4) & 7u;
    const unsigned l  = (i >> 7) & 63u;
    const unsigned p  = (i >> 13) & 255u;
    const unsigned b  = i >> 21;
    const int h = (int)(p >> 4);
    const int w = (int)(p & 15u);
    const int dy = (int)((0xA940u >> (2u * n)) & 3u) - 1;
    const int dx = (int)((0x9224u >> (2u * n)) & 3u) - 1;
    const int hh = h + dy;
    const int ww = w + dx;
    float4 v = zero;
    if ((unsigned)hh < Hh && (unsigned)ww < Ww) {
      // in flat (float4 units): ((b*256 + hh*16 + ww)*64 + l)*16 + c4
      const unsigned src = (b << 18) | ((unsigned)hh << 14) |
                           ((unsigned)ww << 10) | (l << 4) | c4;
      v = in[src];
    }
    out[i] = v;
  }
}

extern "C" void kernel_launch(void* const* d_in, const int* in_sizes, int n_in,
                              void* d_out, int out_size, void* d_ws, size_t ws_size,
                              hipStream_t stream) {
  const float4* in = (const float4*)d_in[0];
  float4* out = (float4*)d_out;
  // 2048 blocks (~8 per CU) x 256 threads, grid-stride: 32 float4 stores/thread
  const int threads = 256;
  const int blocks  = 2048;
  patch_neighbor_gather<<<blocks, threads, 0, stream>>>(in, out);
}

// Round 2
// 283.508 us; speedup vs baseline: 1.0912x; 1.0912x over previous
//
#include <hip/hip_runtime.h>

// Shapes fixed by reference setup_inputs(): B=8, H=W=16, L=64, C=64.
// out[b, p, l, n, c] = E[b, h+dy[n], w+dx[n], l, c]   (0 if neighbor off-grid)
//
// Inverted dataflow: one thread per input float4 (read once, coalesced),
// scatter-store it to the <=8 output rows that reference it, and zero the
// output rows of this thread's OWN patch whose neighbor is off-grid.
// Those two destination sets are disjoint and together cover every output
// float4 exactly once (d_out is poisoned before every launch, so zeros must
// be written explicitly).

typedef float f32x4 __attribute__((ext_vector_type(4)));

constexpr unsigned IN4 = 8u * 256u * 64u * 16u;  // 2^21 input float4s

__global__ __launch_bounds__(256) void patch_scatter(
    const f32x4* __restrict__ in, f32x4* __restrict__ out) {
  const unsigned i = blockIdx.x * 256u + threadIdx.x;  // input float4 index
  // in flat (float4 units): (b<<18) | (p<<10) | (l<<4) | c4
  const unsigned c4 = i & 15u;
  const unsigned l  = (i >> 4) & 63u;
  const unsigned p  = (i >> 10) & 255u;
  const unsigned b  = i >> 18;
  const int h = (int)(p >> 4);
  const int w = (int)(p & 15u);

  const f32x4 v = __builtin_nontemporal_load(&in[i]);
  const f32x4 z = {0.f, 0.f, 0.f, 0.f};

  // out flat (float4 units): (b<<21) | (p'<<13) | (l<<7) | (n<<4) | c4
  const unsigned obase = (b << 21) | (l << 7) | c4;
  const unsigned zbase = obase | (p << 13);

  constexpr int DY[8] = {-1, -1, -1,  0, 0,  1, 1, 1};
  constexpr int DX[8] = {-1,  0,  1, -1, 1, -1, 0, 1};
#pragma unroll
  for (int n = 0; n < 8; ++n) {
    // data scatter: output rows (p' = (h-dy, w-dx), n) read this input row
    const int hh = h - DY[n];
    const int ww = w - DX[n];
    if (((unsigned)hh < 16u) & ((unsigned)ww < 16u)) {
      const unsigned dst =
          obase | ((unsigned)((hh << 4) | ww) << 13) | ((unsigned)n << 4);
      __builtin_nontemporal_store(v, &out[dst]);
    }
    // zero-fill: this thread's own patch row (p, n) if neighbor off-grid
    const int h2 = h + DY[n];
    const int w2 = w + DX[n];
    if (!(((unsigned)h2 < 16u) & ((unsigned)w2 < 16u))) {
      __builtin_nontemporal_store(z, &out[zbase | ((unsigned)n << 4)]);
    }
  }
}

extern "C" void kernel_launch(void* const* d_in, const int* in_sizes, int n_in,
                              void* d_out, int out_size, void* d_ws, size_t ws_size,
                              hipStream_t stream) {
  const f32x4* in = (const f32x4*)d_in[0];
  f32x4* out = (f32x4*)d_out;
  patch_scatter<<<IN4 / 256u, 256, 0, stream>>>(in, out);
}